// Round 3
// baseline (284.790 us; speedup 1.0000x reference)
//
#include <hip/hip_runtime.h>

typedef float v2f __attribute__((ext_vector_type(2)));

#define DD   187   // input dim
#define HH   50    // hidden
#define PH   56    // padded hidden (4 groups of 14)
#define HPJ  14    // hidden neurons per lane of quad
#define NP   7     // float2 pairs per lane
#define NC   5     // classes
#define RPB  64    // rows per block
#define BLK  256   // threads per block
#define DCH  64    // d-chunk
#define NCHUNK 3   // ceil(187/64)
#define BETA 0.9f
#define GRP  10    // steps buffered in registers between store bursts

__device__ __forceinline__ float dpp_xor1(float v) {
    return __builtin_bit_cast(float,
        __builtin_amdgcn_mov_dpp(__builtin_bit_cast(int, v), 0xB1, 0xF, 0xF, true));
}
__device__ __forceinline__ float dpp_xor2(float v) {
    return __builtin_bit_cast(float,
        __builtin_amdgcn_mov_dpp(__builtin_bit_cast(int, v), 0x4E, 0xF, 0xF, true));
}

__device__ __forceinline__ float spike1(float m) {
    // exact (m > 1) ? 1 : 0
    float t = fmaf(m, 0x1.0p60f, -0x1.0p60f);
    return fminf(fmaxf(t, 0.f), 1.f);
}
__device__ __forceinline__ v2f spike2(v2f m) {
    const v2f BIG2  = { 0x1.0p60f,  0x1.0p60f};
    const v2f NBIG2 = {-0x1.0p60f, -0x1.0p60f};
    const v2f ONE2  = {1.f, 1.f};
    const v2f ZERO2 = {0.f, 0.f};
    v2f t = __builtin_elementwise_fma(m, BIG2, NBIG2);
    return __builtin_elementwise_min(__builtin_elementwise_max(t, ZERO2), ONE2);
}

__global__ __launch_bounds__(BLK, 2)
void snn_kernel(const float* __restrict__ x,
                const float* __restrict__ W1,
                const float* __restrict__ b1,
                const float* __restrict__ W2,
                const float* __restrict__ b2,
                const int*   __restrict__ nsp,
                float* __restrict__ out, int Brows)
{
    __shared__ float xs[RPB * 65];
    __shared__ float w1t[DCH * PH];

    const int tid = threadIdx.x;
    const int p   = tid >> 2;
    const int k   = tid & 3;
    const int row = blockIdx.x * RPB + p;
    const int NS  = nsp[0];

    // ---------------- Phase 1: cur1 = x @ W1^T ----------------
    v2f acc[NP];
#pragma unroll
    for (int i = 0; i < NP; ++i) acc[i] = (v2f){0.f, 0.f};

    for (int ch = 0; ch < NCHUNK; ++ch) {
        const int d0 = ch * DCH;
        for (int i = tid; i < RPB * DCH; i += BLK) {
            int r = i >> 6, dd = i & 63;
            int d = d0 + dd;
            xs[r * 65 + dd] = (d < DD) ? x[(size_t)(blockIdx.x * RPB + r) * DD + d] : 0.f;
        }
        for (int i = tid; i < DCH * PH; i += BLK) {
            int h = i >> 6, dd = i & 63;
            int d = d0 + dd;
            w1t[dd * PH + h] = (h < HH && d < DD) ? W1[h * DD + d] : 0.f;
        }
        __syncthreads();

        const float* xr = xs + p * 65;
#pragma unroll 4
        for (int d = 0; d < DCH; ++d) {
            float xv = xr[d];
            const v2f* wr = (const v2f*)(w1t + d * PH + k * HPJ);
            v2f xvv = {xv, xv};
#pragma unroll
            for (int i = 0; i < NP; ++i)
                acc[i] = __builtin_elementwise_fma(xvv, wr[i], acc[i]);
        }
        __syncthreads();
    }

    v2f c1[NP];
#pragma unroll
    for (int i = 0; i < NP; ++i) {
        int h0 = k * HPJ + 2 * i;
        v2f bb = { (h0     < HH) ? b1[h0]     : 0.f,
                   (h0 + 1 < HH) ? b1[h0 + 1] : 0.f };
        c1[i] = acc[i] + bb;
    }

    v2f w2r[NC][NP];
#pragma unroll
    for (int c = 0; c < NC; ++c)
#pragma unroll
        for (int i = 0; i < NP; ++i) {
            int h0 = k * HPJ + 2 * i;
            w2r[c][i] = { (h0     < HH) ? W2[c * HH + h0]     : 0.f,
                          (h0 + 1 < HH) ? W2[c * HH + h0 + 1] : 0.f };
        }
    const float b2A = b2[k];
    const float b2B = b2[4];

    // ---------------- Phase 2: LIF recurrence, GRP-step store bursts ----------------
    v2f m1[NP], s1[NP];
#pragma unroll
    for (int i = 0; i < NP; ++i) { m1[i] = (v2f){0.f, 0.f}; s1[i] = (v2f){0.f, 0.f}; }
    float mA = 0.f, sA = 0.f, mB = 0.f, sB = 0.f;

    const size_t stride = (size_t)Brows * NC;
    float* spkBase = out;
    float* memBase = out + (size_t)NS * stride;
    const int offA = row * NC + k;
    const int offB = row * NC + 4;
    const v2f BETA2 = {BETA, BETA};

    float sbA[GRP], mbA[GRP], sbB[GRP], mbB[GRP];

    const int ngrp = NS / GRP;
    for (int g = 0; g < ngrp; ++g) {
#pragma unroll
        for (int u = 0; u < GRP; ++u) {
            v2f cp[NC];
#pragma unroll
            for (int c = 0; c < NC; ++c) cp[c] = (v2f){0.f, 0.f};
#pragma unroll
            for (int i = 0; i < NP; ++i) {
                v2f m = __builtin_elementwise_fma(BETA2, m1[i], c1[i]) - s1[i];
                m1[i] = m;
                v2f s = spike2(m);
                s1[i] = s;
#pragma unroll
                for (int c = 0; c < NC; ++c)
                    cp[c] = __builtin_elementwise_fma(s, w2r[c][i], cp[c]);
            }
            float cur2[NC];
#pragma unroll
            for (int c = 0; c < NC; ++c) {
                float r = cp[c].x + cp[c].y;
                r += dpp_xor1(r);
                r += dpp_xor2(r);
                cur2[c] = r;
            }
            float cA = (k == 0) ? cur2[0] : (k == 1) ? cur2[1] : (k == 2) ? cur2[2] : cur2[3];
            float cB = cur2[4];

            mA = fmaf(BETA, mA, cA + b2A) - sA;
            sA = spike1(mA);
            mB = fmaf(BETA, mB, cB + b2B) - sB;
            sB = spike1(mB);

            sbA[u] = sA; mbA[u] = mA; sbB[u] = sB; mbB[u] = mB;
        }
        // burst store GRP steps (same order as buffer overwrite next group ->
        // fine-grained vmcnt drain, no per-step round trip)
#pragma unroll
        for (int u = 0; u < GRP; ++u) {
            float* sp = spkBase + (size_t)u * stride;
            float* mp = memBase + (size_t)u * stride;
            __builtin_nontemporal_store(sbA[u], sp + offA);
            __builtin_nontemporal_store(mbA[u], mp + offA);
        }
        if (k == 0) {
#pragma unroll
            for (int u = 0; u < GRP; ++u) {
                float* sp = spkBase + (size_t)u * stride;
                float* mp = memBase + (size_t)u * stride;
                __builtin_nontemporal_store(sbB[u], sp + offB);
                __builtin_nontemporal_store(mbB[u], mp + offB);
            }
        }
        spkBase += (size_t)GRP * stride;
        memBase += (size_t)GRP * stride;
    }

    // remainder steps (NS not divisible by GRP)
    for (int t = ngrp * GRP; t < NS; ++t) {
        v2f cp[NC];
#pragma unroll
        for (int c = 0; c < NC; ++c) cp[c] = (v2f){0.f, 0.f};
#pragma unroll
        for (int i = 0; i < NP; ++i) {
            v2f m = __builtin_elementwise_fma(BETA2, m1[i], c1[i]) - s1[i];
            m1[i] = m;
            v2f s = spike2(m);
            s1[i] = s;
#pragma unroll
            for (int c = 0; c < NC; ++c)
                cp[c] = __builtin_elementwise_fma(s, w2r[c][i], cp[c]);
        }
        float cur2[NC];
#pragma unroll
        for (int c = 0; c < NC; ++c) {
            float r = cp[c].x + cp[c].y;
            r += dpp_xor1(r);
            r += dpp_xor2(r);
            cur2[c] = r;
        }
        float cA = (k == 0) ? cur2[0] : (k == 1) ? cur2[1] : (k == 2) ? cur2[2] : cur2[3];
        float cB = cur2[4];
        mA = fmaf(BETA, mA, cA + b2A) - sA;
        sA = spike1(mA);
        mB = fmaf(BETA, mB, cB + b2B) - sB;
        sB = spike1(mB);
        spkBase[offA] = sA;
        memBase[offA] = mA;
        if (k == 0) { spkBase[offB] = sB; memBase[offB] = mB; }
        spkBase += stride;
        memBase += stride;
    }
}

extern "C" void kernel_launch(void* const* d_in, const int* in_sizes, int n_in,
                              void* d_out, int out_size, void* d_ws, size_t ws_size,
                              hipStream_t stream) {
    const float* x  = (const float*)d_in[0];
    const float* W1 = (const float*)d_in[1];
    const float* b1 = (const float*)d_in[2];
    const float* W2 = (const float*)d_in[3];
    const float* b2 = (const float*)d_in[4];
    const int*   ns = (const int*)d_in[5];
    int B = in_sizes[0] / DD;          // 32768
    int nblocks = B / RPB;             // 512 -> 2 blocks/CU
    snn_kernel<<<nblocks, BLK, 0, stream>>>(x, W1, b1, W2, b2, ns, (float*)d_out, B);
}

// Round 4
// 220.795 us; speedup vs baseline: 1.2898x; 1.2898x over previous
//
#include <hip/hip_runtime.h>

typedef float v2f __attribute__((ext_vector_type(2)));
typedef float f4  __attribute__((ext_vector_type(4)));

#define DD   187   // input dim
#define HH   50    // hidden
#define PH   56    // padded hidden (4 groups of 14)
#define HPJ  14    // hidden neurons per lane of quad
#define NP   7     // float2 pairs per lane
#define NC   5     // classes
#define RPB  64    // rows per block
#define BLK  256   // threads per block
#define DCH  64    // d-chunk
#define NCHUNK 3   // ceil(187/64)
#define BETA 0.9f
#define GRP  16    // steps staged in LDS between global flushes
#define SLAB (RPB * NC)         // 320 dwords per step per slab
#define LDSF (2 * GRP * SLAB)   // 10240 floats = 40 KB total

__device__ __forceinline__ float dpp_xor1(float v) {
    return __builtin_bit_cast(float,
        __builtin_amdgcn_mov_dpp(__builtin_bit_cast(int, v), 0xB1, 0xF, 0xF, true));
}
__device__ __forceinline__ float dpp_xor2(float v) {
    return __builtin_bit_cast(float,
        __builtin_amdgcn_mov_dpp(__builtin_bit_cast(int, v), 0x4E, 0xF, 0xF, true));
}

__device__ __forceinline__ float spike1(float m) {
    // exact (m > 1) ? 1 : 0
    float t = fmaf(m, 0x1.0p60f, -0x1.0p60f);
    return fminf(fmaxf(t, 0.f), 1.f);
}
__device__ __forceinline__ v2f spike2(v2f m) {
    const v2f BIG2  = { 0x1.0p60f,  0x1.0p60f};
    const v2f NBIG2 = {-0x1.0p60f, -0x1.0p60f};
    const v2f ONE2  = {1.f, 1.f};
    const v2f ZERO2 = {0.f, 0.f};
    v2f t = __builtin_elementwise_fma(m, BIG2, NBIG2);
    return __builtin_elementwise_min(__builtin_elementwise_max(t, ZERO2), ONE2);
}

__global__ __launch_bounds__(BLK, 2)
void snn_kernel(const float* __restrict__ x,
                const float* __restrict__ W1,
                const float* __restrict__ b1,
                const float* __restrict__ W2,
                const float* __restrict__ b2,
                const int*   __restrict__ nsp,
                float* __restrict__ out, int Brows)
{
    // one buffer, two lives: phase1 {xs | w1t}, phase2 {spk slab | mem slab}
    __shared__ alignas(16) float smem[LDSF];
    float* xs  = smem;                 // RPB*65 = 4160 floats
    float* w1t = smem + RPB * 65;      // DCH*PH = 3584 floats (ends at 7744 < 10240)
    float* spk_lds = smem;             // GRP*SLAB = 5120 floats
    float* mem_lds = smem + GRP * SLAB;

    const int tid = threadIdx.x;
    const int p   = tid >> 2;          // row within block (quad id)
    const int k   = tid & 3;           // lane within quad
    const int row0 = blockIdx.x * RPB;
    const int NS  = nsp[0];

    // ---------------- Phase 1: cur1 = x @ W1^T ----------------
    v2f acc[NP];
#pragma unroll
    for (int i = 0; i < NP; ++i) acc[i] = (v2f){0.f, 0.f};

    for (int ch = 0; ch < NCHUNK; ++ch) {
        const int d0 = ch * DCH;
        for (int i = tid; i < RPB * DCH; i += BLK) {
            int r = i >> 6, dd = i & 63;
            int d = d0 + dd;
            xs[r * 65 + dd] = (d < DD) ? x[(size_t)(row0 + r) * DD + d] : 0.f;
        }
        for (int i = tid; i < DCH * PH; i += BLK) {
            int h = i >> 6, dd = i & 63;
            int d = d0 + dd;
            w1t[dd * PH + h] = (h < HH && d < DD) ? W1[h * DD + d] : 0.f;
        }
        __syncthreads();

        const float* xr = xs + p * 65;
#pragma unroll 4
        for (int d = 0; d < DCH; ++d) {
            float xv = xr[d];
            const v2f* wr = (const v2f*)(w1t + d * PH + k * HPJ);
            v2f xvv = {xv, xv};
#pragma unroll
            for (int i = 0; i < NP; ++i)
                acc[i] = __builtin_elementwise_fma(xvv, wr[i], acc[i]);
        }
        __syncthreads();
    }

    v2f c1[NP];
#pragma unroll
    for (int i = 0; i < NP; ++i) {
        int h0 = k * HPJ + 2 * i;
        v2f bb = { (h0     < HH) ? b1[h0]     : 0.f,
                   (h0 + 1 < HH) ? b1[h0 + 1] : 0.f };
        c1[i] = acc[i] + bb;
    }

    v2f w2r[NC][NP];
#pragma unroll
    for (int c = 0; c < NC; ++c)
#pragma unroll
        for (int i = 0; i < NP; ++i) {
            int h0 = k * HPJ + 2 * i;
            w2r[c][i] = { (h0     < HH) ? W2[c * HH + h0]     : 0.f,
                          (h0 + 1 < HH) ? W2[c * HH + h0 + 1] : 0.f };
        }
    const float b2A = b2[k];   // lane k owns class k
    const float b2B = b2[4];   // lane 0 additionally owns class 4

    // ---------------- Phase 2: LIF recurrence, LDS-staged outputs ----------------
    v2f m1[NP], s1[NP];
#pragma unroll
    for (int i = 0; i < NP; ++i) { m1[i] = (v2f){0.f, 0.f}; s1[i] = (v2f){0.f, 0.f}; }
    float mA = 0.f, sA = 0.f, mB = 0.f, sB = 0.f;

    const size_t stride = (size_t)Brows * NC;
    const int p5k = p * NC + k;        // LDS slot within a step-slab
    const v2f BETA2 = {BETA, BETA};

    // barrier between phase-1 LDS reads and slab overwrite
    __syncthreads();

    int t0 = 0;
    while (t0 < NS) {
        const int steps = (NS - t0 < GRP) ? (NS - t0) : GRP;

        for (int u = 0; u < steps; ++u) {
            v2f cp[NC];
#pragma unroll
            for (int c = 0; c < NC; ++c) cp[c] = (v2f){0.f, 0.f};
#pragma unroll
            for (int i = 0; i < NP; ++i) {
                // mem1 = beta*mem1 + cur1 - reset1 (reset1 == previous spike)
                v2f m = __builtin_elementwise_fma(BETA2, m1[i], c1[i]) - s1[i];
                m1[i] = m;
                v2f s = spike2(m);
                s1[i] = s;
#pragma unroll
                for (int c = 0; c < NC; ++c)
                    cp[c] = __builtin_elementwise_fma(s, w2r[c][i], cp[c]);
            }
            float cur2[NC];
#pragma unroll
            for (int c = 0; c < NC; ++c) {
                float r = cp[c].x + cp[c].y;
                r += dpp_xor1(r);
                r += dpp_xor2(r);
                cur2[c] = r;
            }
            float cA = (k == 0) ? cur2[0] : (k == 1) ? cur2[1] : (k == 2) ? cur2[2] : cur2[3];
            float cB = cur2[4];

            mA = fmaf(BETA, mA, cA + b2A) - sA;
            sA = spike1(mA);
            mB = fmaf(BETA, mB, cB + b2B) - sB;
            sB = spike1(mB);

            // stage to LDS — no global stores (and no vmcnt) in the recurrence
            spk_lds[u * SLAB + p5k] = sA;
            mem_lds[u * SLAB + p5k] = mA;
            if (k == 0) {
                spk_lds[u * SLAB + p * NC + 4] = sB;
                mem_lds[u * SLAB + p * NC + 4] = mB;
            }
        }

        __syncthreads();   // slab complete

        // cooperative flush: 16B-aligned dwordx4, fully coalesced.
        // chunk = one 16B quad of a step-slab; 80 chunks per step.
        const int totalChunks = steps * (SLAB / 4);
        for (int c = tid; c < totalChunks; c += BLK) {
            int u   = c / (SLAB / 4);
            int pos = c - u * (SLAB / 4);
            f4 sv = *(const f4*)(spk_lds + u * SLAB + pos * 4);
            f4 mv = *(const f4*)(mem_lds + u * SLAB + pos * 4);
            float* sp = out + (size_t)(t0 + u) * stride + (size_t)row0 * NC + pos * 4;
            float* mp = sp + (size_t)NS * stride;
            *(f4*)sp = sv;
            *(f4*)mp = mv;
        }

        __syncthreads();   // slab free for reuse
        t0 += steps;
    }
}

extern "C" void kernel_launch(void* const* d_in, const int* in_sizes, int n_in,
                              void* d_out, int out_size, void* d_ws, size_t ws_size,
                              hipStream_t stream) {
    const float* x  = (const float*)d_in[0];
    const float* W1 = (const float*)d_in[1];
    const float* b1 = (const float*)d_in[2];
    const float* W2 = (const float*)d_in[3];
    const float* b2 = (const float*)d_in[4];
    const int*   ns = (const int*)d_in[5];
    int B = in_sizes[0] / DD;          // 32768
    int nblocks = B / RPB;             // 512 -> 2 blocks/CU
    snn_kernel<<<nblocks, BLK, 0, stream>>>(x, W1, b1, W2, b2, ns, (float*)d_out, B);
}